// Round 19
// baseline (149.434 us; speedup 1.0000x reference)
//
#include <hip/hip_runtime.h>
#include <hip/hip_bf16.h>
#include <stdint.h>

typedef __attribute__((ext_vector_type(4))) float f32x4;
typedef __attribute__((ext_vector_type(16))) float f32x16;
typedef __attribute__((ext_vector_type(4))) int i32x4;
typedef __attribute__((ext_vector_type(8))) int i32x8;
typedef long long ll64;
typedef __attribute__((ext_vector_type(2))) long long ll64x2;

__device__ __forceinline__ float fast_exp2(float x){
#if __has_builtin(__builtin_amdgcn_exp2f)
  return __builtin_amdgcn_exp2f(x);
#else
  return exp2f(x);
#endif
}
__device__ __forceinline__ unsigned char f2fp8(float f){
#if __has_builtin(__builtin_amdgcn_cvt_pk_fp8_f32)
  int r = __builtin_amdgcn_cvt_pk_fp8_f32(f, f, 0, false);
  return (unsigned char)(r & 0xff);
#else
  uint32_t u = __builtin_bit_cast(uint32_t, f);
  uint32_t s = (u >> 24) & 0x80u;
  uint32_t a = u & 0x7fffffffu;
  float af = __builtin_bit_cast(float, a);
  if (af >= 448.f) return (unsigned char)(s | 0x7e);
  a += 0x000fffffu + ((a >> 20) & 1u);
  int e = (int)(a >> 23) - 127;
  if (e < -6) return (unsigned char)s;
  return (unsigned char)(s | (uint32_t)((e + 7) << 3) | ((a >> 20) & 7u));
#endif
}
__device__ __forceinline__ uint32_t pack4(float a, float b, float c, float d){
#if __has_builtin(__builtin_amdgcn_cvt_pk_fp8_f32)
  int lo = __builtin_amdgcn_cvt_pk_fp8_f32(a, b, 0, false);
  int r  = __builtin_amdgcn_cvt_pk_fp8_f32(c, d, lo, true);
  return (uint32_t)r;
#else
  return (uint32_t)f2fp8(a) | ((uint32_t)f2fp8(b) << 8) |
         ((uint32_t)f2fp8(c) << 16) | ((uint32_t)f2fp8(d) << 24);
#endif
}
// k-interleave permutation; for 4-aligned c: perm64(c+q)=perm64(c)+q, q<4.
// Also perm64(base+l) = base + perm64(l) when base is a multiple of 64.
__device__ __forceinline__ int perm64(int c){
  return (c & ~63) | (((c >> 3) & 3) << 4) | (((c >> 5) & 1) << 3) | (c & 7);
}
__device__ __forceinline__ void gl_lds16b(const unsigned char* g, unsigned char* l){
  __builtin_amdgcn_global_load_lds(
      (const __attribute__((address_space(1))) uint32_t*)g,
      (__attribute__((address_space(3))) uint32_t*)l, 16, 0, 0);
}

// 32x32 K=64 fp8 MFMA: scaled-MX with unit scales (2.3x rate) or 4x non-scaled fallback
__device__ __forceinline__ f32x16 mfma8_32x32x64(i32x8 a, i32x8 b, f32x16 c){
#if __has_builtin(__builtin_amdgcn_mfma_scale_f32_32x32x64_f8f6f4)
  return __builtin_amdgcn_mfma_scale_f32_32x32x64_f8f6f4(a, b, c, 0, 0,
                                                         0, 0x7f7f7f7f, 0, 0x7f7f7f7f);
#else
  ll64x2 al = __builtin_bit_cast(ll64x2, *(i32x4*)&a);
  ll64x2 ah; ah[0] = ((ll64*)&a)[2]; ah[1] = ((ll64*)&a)[3];
  ll64x2 bl = __builtin_bit_cast(ll64x2, *(i32x4*)&b);
  ll64x2 bh; bh[0] = ((ll64*)&b)[2]; bh[1] = ((ll64*)&b)[3];
  c = __builtin_amdgcn_mfma_f32_32x32x16_fp8_fp8(al[0], bl[0], c, 0, 0, 0);
  c = __builtin_amdgcn_mfma_f32_32x32x16_fp8_fp8(al[1], bl[1], c, 0, 0, 0);
  c = __builtin_amdgcn_mfma_f32_32x32x16_fp8_fp8(ah[0], bh[0], c, 0, 0, 0);
  c = __builtin_amdgcn_mfma_f32_32x32x16_fp8_fp8(ah[1], bh[1], c, 0, 0, 0);
  return c;
#endif
}

// ---------------- fused prep: GN partial stats (0..1023) + weight fp8 convert (1024..1535) ----
__global__ __launch_bounds__(256) void k_prep(const float* __restrict__ x,
                                              float* __restrict__ part,
                                              const float* __restrict__ Wq, const float* __restrict__ Wk,
                                              const float* __restrict__ Wv, const float* __restrict__ Wo,
                                              unsigned char* __restrict__ oqk,
                                              unsigned char* __restrict__ ov,
                                              unsigned char* __restrict__ oo){
  __shared__ float red[8];
  const int bid = blockIdx.x;
  if (bid < 1024) {
    const float* p = x + (size_t)bid * 8192;
    float s = 0.f, ss = 0.f;
    for (int i = threadIdx.x; i < 2048; i += 256) {
      float4 v = *(const float4*)(p + (size_t)i * 4);
      s  += v.x + v.y + v.z + v.w;
      ss += v.x*v.x + v.y*v.y + v.z*v.z + v.w*v.w;
    }
    for (int off = 32; off; off >>= 1) { s += __shfl_down(s, off); ss += __shfl_down(ss, off); }
    int w = threadIdx.x >> 6;
    if ((threadIdx.x & 63) == 0) { red[w] = s; red[w + 4] = ss; }
    __syncthreads();
    if (threadIdx.x == 0) {
      part[bid * 2]     = red[0] + red[1] + red[2] + red[3];
      part[bid * 2 + 1] = red[4] + red[5] + red[6] + red[7];
    }
  } else {
    const int cb = bid - 1024;
    const int sel = cb >> 7;
    const float* in = sel == 0 ? Wq : sel == 1 ? Wk : sel == 2 ? Wv : Wo;
    unsigned char* out = sel == 0 ? oqk : sel == 1 ? (oqk + 262144) : sel == 2 ? ov : oo;
    const int i = ((cb & 127) * 256 + threadIdx.x) * 8;
    const int row = i >> 9;
    const int c0  = i & 511;
    float4 v0 = *(const float4*)&in[i];
    float4 v1 = *(const float4*)&in[i + 4];
    unsigned char o[8];
    o[0]=f2fp8(v0.x); o[1]=f2fp8(v0.y); o[2]=f2fp8(v0.z); o[3]=f2fp8(v0.w);
    o[4]=f2fp8(v1.x); o[5]=f2fp8(v1.y); o[6]=f2fp8(v1.z); o[7]=f2fp8(v1.w);
    *(ll64*)&out[row * 512 + perm64(c0)] = *(ll64*)o;
  }
}

// ---------------- GN apply + transpose -> fp8 k-interleaved; final stat reduce inline ----------------
__global__ __launch_bounds__(256) void gn_apply(const float* __restrict__ x,
                                                const float* __restrict__ spart,
                                                const float* __restrict__ gamma,
                                                const float* __restrict__ beta,
                                                unsigned char* __restrict__ hn8){
  __shared__ float tile[64][33];
  const int b  = blockIdx.z;
  const int c0 = blockIdx.y * 64;
  const int p0 = blockIdx.x * 32;
  const int t  = threadIdx.x;
  const float* xb = x + (size_t)b * 512 * 4096;
  const int lpx = t & 31, lcc = t >> 5;
#pragma unroll
  for (int i = 0; i < 8; i++)
    tile[lcc + i * 8][lpx] = xb[(size_t)(c0 + lcc + i * 8) * 4096 + p0 + lpx];
  __syncthreads();
  unsigned char* hb = hn8 + (size_t)b * 4096 * 512;
  const int c   = c0 + (t & 31) * 2;
  const int pxi = t >> 5;
  const int g2  = b * 32 + (c >> 4);
  float sum = 0.f, ssum = 0.f;
#pragma unroll
  for (int i = 0; i < 8; i++) { sum += spart[(g2 * 8 + i) * 2]; ssum += spart[(g2 * 8 + i) * 2 + 1]; }
  const float mean = sum * (1.f / 65536.f);
  const float rstd = rsqrtf(ssum * (1.f / 65536.f) - mean * mean + 1e-6f);
  const float ga0 = gamma[c], be0 = beta[c];
  const float ga1 = gamma[c + 1], be1 = beta[c + 1];
  const int cp = perm64(c);
#pragma unroll
  for (int i = 0; i < 4; i++) {
    const int px = pxi + i * 8;
    float v0 = tile[(t & 31) * 2][px];
    float v1 = tile[(t & 31) * 2 + 1][px];
    unsigned int b0 = f2fp8((v0 - mean) * rstd * ga0 + be0);
    unsigned int b1 = f2fp8((v1 - mean) * rstd * ga1 + be1);
    *(unsigned short*)&hb[(size_t)(p0 + px) * 512 + cp] = (unsigned short)(b0 | (b1 << 8));
  }
}

// ---------------- unified scaled-fp8 GEMM body; LDS-transpose coalesced epilogues ----------------
// BM=128 (rows = pack dim), BN=128 (cols = lane dim), BK=64, NBUF=2.
// MODE 1 qkproj: A=Wqk[ch][k], B=hn[tok][k]; tile[ch][tok] -> qk8[tok][perm(ch)] via LDS
// MODE 2 vproj : A=hn[tok][k], B=Wv[ch][k]; tile[tok][ch] -> vcm8[b][ch][perm(p)] via LDS
// MODE 4 pv    : A=vcm8[c][key], B=P8[q][key]; *rinv(q)   -> ot8[tok][perm(c)] via LDS
// MODE 5 oproj : A=Wo[ch][k], B=ot8[tok][k]; +resid+bias  -> fp32 out (lane-coalesced in p)
template<int MODE>
__device__ __forceinline__ void gemm8_body(
    int wg, unsigned char* smem,
    const unsigned char* __restrict__ A, const unsigned char* __restrict__ B,
    unsigned char* __restrict__ C8, float* __restrict__ OUTF,
    const float* __restrict__ auxA, const float* __restrict__ auxB,
    const float* __restrict__ partial,
    int K, int ldA, int ldB,
    size_t sA, size_t sB, int gx, int gy)
{
  unsigned char* As = smem;
  unsigned char* Bs = smem + 16384;

  const int bx = wg % gx;
  const int t2 = wg / gx;
  const int by = t2 % gy;
  const int bz = t2 / gy;

  const unsigned char* Ab = A + (size_t)bz * sA;
  const unsigned char* Bb = B + (size_t)bz * sB;
  const int brow = bx * 128;
  const int bcol = by * 128;
  const int t = threadIdx.x;
  const int lane = t & 63;
  const int wid = t >> 6;
  const int wr = wid >> 2;        // 0..1 (64 rows)
  const int wc = wid & 3;         // 0..3 (32 cols)
  const int l31 = lane & 31;
  const int lh  = lane >> 5;

  f32x16 acc[2];
#pragma unroll
  for (int m = 0; m < 2; m++)
#pragma unroll
    for (int e = 0; e < 16; e++) acc[m][e] = 0.f;

  const unsigned char* srcA1;
  const unsigned char* srcB1;
  {
    const int r = t >> 2, s = (t & 3) ^ ((r >> 1) & 3);
    srcA1 = Ab + (size_t)(brow + r) * ldA + s * 16;
    srcB1 = Bb + (size_t)(bcol + r) * ldB + s * 16;
  }
  auto STAGE = [&](int kt, int buf) {
    const int ko = kt * 64;
    gl_lds16b(srcA1 + ko, &As[buf * 8192 + t * 16]);
    gl_lds16b(srcB1 + ko, &Bs[buf * 8192 + t * 16]);
  };
  auto LDA32 = [&](int buf, int mb) -> i32x8 {
    const int ru = wr * 64 + mb * 32 + l31;
    const int x = (ru >> 1) & 3;
    const unsigned char* base = &As[buf * 8192 + ru * 64];
    i32x4 lo = *(const i32x4*)&base[((2 * lh) ^ x) * 16];
    i32x4 hi = *(const i32x4*)&base[((2 * lh + 1) ^ x) * 16];
    i32x8 r;
    r[0]=lo[0]; r[1]=lo[1]; r[2]=lo[2]; r[3]=lo[3];
    r[4]=hi[0]; r[5]=hi[1]; r[6]=hi[2]; r[7]=hi[3];
    return r;
  };
  auto LDB32 = [&](int buf) -> i32x8 {
    const int ru = wc * 32 + l31;
    const int x = (ru >> 1) & 3;
    const unsigned char* base = &Bs[buf * 8192 + ru * 64];
    i32x4 lo = *(const i32x4*)&base[((2 * lh) ^ x) * 16];
    i32x4 hi = *(const i32x4*)&base[((2 * lh + 1) ^ x) * 16];
    i32x8 r;
    r[0]=lo[0]; r[1]=lo[1]; r[2]=lo[2]; r[3]=lo[3];
    r[4]=hi[0]; r[5]=hi[1]; r[6]=hi[2]; r[7]=hi[3];
    return r;
  };

  const int nk = K >> 6;
  STAGE(0, 0);
  for (int j = 0; j < nk; ++j) {
    const int bi = j & 1;
    asm volatile("s_waitcnt vmcnt(0)" ::: "memory");
    __builtin_amdgcn_s_barrier();
    __builtin_amdgcn_sched_barrier(0);
    if (j + 1 < nk) STAGE(j + 1, bi ^ 1);
    i32x8 aq[2], bq;
    bq = LDB32(bi);
#pragma unroll
    for (int m = 0; m < 2; m++) aq[m] = LDA32(bi, m);
    asm volatile("s_waitcnt lgkmcnt(0)" ::: "memory");
    __builtin_amdgcn_sched_barrier(0);
    __builtin_amdgcn_s_setprio(1);
#pragma unroll
    for (int m = 0; m < 2; m++)
      acc[m] = mfma8_32x32x64(aq[m], bq, acc[m]);
    __builtin_amdgcn_s_setprio(0);
    __builtin_amdgcn_sched_barrier(0);
  }

  // epilogues (32x32 C/D: col=lane&31, row=(reg&3)+8*(reg>>2)+4*(lane>>5))
  const int lcol = wc * 32 + l31;          // block-local col (lane dim)

  if (MODE == 1) {
    // tile[ch rows][tok cols]; out qk8[tok][perm(ch)]
    asm volatile("s_waitcnt lgkmcnt(0)" ::: "memory");
    __builtin_amdgcn_s_barrier();
#pragma unroll
    for (int mb = 0; mb < 2; mb++)
#pragma unroll
      for (int g = 0; g < 4; g++) {
        const int lch0 = wr * 64 + mb * 32 + g * 8 + 4 * lh;
        const int ch0 = brow + lch0;
        const float4 b4 = *(const float4*)((ch0 < 512) ? (auxA + ch0) : (auxB + ch0 - 512));
        const int cpL = perm64(lch0 & 127) | (lch0 & 64);   // local perm within 128
        uint32_t w = pack4(acc[mb][g*4+0] + b4.x, acc[mb][g*4+1] + b4.y,
                           acc[mb][g*4+2] + b4.z, acc[mb][g*4+3] + b4.w);
        *(uint32_t*)&smem[lcol * 128 + ((cpL & 127) ^ ((lcol & 7) << 4))] = w;
      }
    __builtin_amdgcn_s_barrier();
    unsigned char* dst = C8 + (brow < 512 ? 0 : (size_t)8388608);
    const int chb = brow & 511;
#pragma unroll
    for (int i = 0; i < 2; i++) {
      const int ch = i * 512 + t;
      const int rl = ch >> 3, c16 = (ch & 7) * 16;
      i32x4 v = *(const i32x4*)&smem[rl * 128 + (c16 ^ ((rl & 7) << 4))];
      *(i32x4*)&dst[(size_t)(bcol + rl) * 512 + chb + c16] = v;
    }
  } else if (MODE == 2) {
    // tile[tok rows][ch cols]; out vcm8[b][ch][perm(p)]
    const float bcv = auxA[bcol + lcol];
    asm volatile("s_waitcnt lgkmcnt(0)" ::: "memory");
    __builtin_amdgcn_s_barrier();
#pragma unroll
    for (int mb = 0; mb < 2; mb++)
#pragma unroll
      for (int g = 0; g < 4; g++) {
        const int lt0 = wr * 64 + mb * 32 + g * 8 + 4 * lh;    // local tok
        const int ppL = perm64(lt0 & 63) | (lt0 & 64);
        uint32_t w = pack4(acc[mb][g*4+0] + bcv, acc[mb][g*4+1] + bcv,
                           acc[mb][g*4+2] + bcv, acc[mb][g*4+3] + bcv);
        *(uint32_t*)&smem[lcol * 128 + (ppL ^ ((lcol & 7) << 4))] = w;
      }
    __builtin_amdgcn_s_barrier();
    const int bb = brow >> 12;
    const int pb = brow & 4095;
#pragma unroll
    for (int i = 0; i < 2; i++) {
      const int ch = i * 512 + t;
      const int rl = ch >> 3, c16 = (ch & 7) * 16;
      i32x4 v = *(const i32x4*)&smem[rl * 128 + (c16 ^ ((rl & 7) << 4))];
      *(i32x4*)&C8[((size_t)bb * 512 + bcol + rl) * 4096 + pb + c16] = v;
    }
  } else if (MODE == 4) {
    // rinv for q in [bcol,bcol+128) from partial[bz][32][4096]
    float* rtmp  = (float*)(smem + 32768);
    float* rinvL = (float*)(smem + 32768 + 2048);
    {
      const int row = t >> 2, q4 = t & 3;
      const float* pb = partial + ((size_t)bz * 32 + q4 * 8) * 4096 + (bcol + row);
      float s = 0.f;
#pragma unroll
      for (int i = 0; i < 8; i++) s += pb[(size_t)i * 4096];
      rtmp[row * 4 + q4] = s;
    }
    __syncthreads();
    if (t < 128) rinvL[t] = 1.f / (rtmp[t * 4] + rtmp[t * 4 + 1] + rtmp[t * 4 + 2] + rtmp[t * 4 + 3]);
    __syncthreads();
    const float ri = rinvL[lcol];
#pragma unroll
    for (int mb = 0; mb < 2; mb++)
#pragma unroll
      for (int g = 0; g < 4; g++) {
        const int lch0 = wr * 64 + mb * 32 + g * 8 + 4 * lh;
        const int cpL = perm64(lch0 & 63) | (lch0 & 64);
        uint32_t w = pack4(acc[mb][g*4+0] * ri, acc[mb][g*4+1] * ri,
                           acc[mb][g*4+2] * ri, acc[mb][g*4+3] * ri);
        *(uint32_t*)&smem[lcol * 128 + (cpL ^ ((lcol & 7) << 4))] = w;
      }
    __builtin_amdgcn_s_barrier();
#pragma unroll
    for (int i = 0; i < 2; i++) {
      const int ch = i * 512 + t;
      const int rl = ch >> 3, c16 = (ch & 7) * 16;
      i32x4 v = *(const i32x4*)&smem[rl * 128 + (c16 ^ ((rl & 7) << 4))];
      *(i32x4*)&C8[((size_t)bz * 4096 + bcol + rl) * 512 + brow + c16] = v;
    }
  } else { // MODE 5: rows=ch (Wo), cols=tok; coalesced-in-p resid/out
    const int tok = bcol + lcol;
    const int bb = tok >> 12;
    const int p  = tok & 4095;
#pragma unroll
    for (int mb = 0; mb < 2; mb++)
#pragma unroll
      for (int g = 0; g < 4; g++) {
        const int ch0 = brow + wr * 64 + mb * 32 + g * 8 + 4 * lh;
        const float4 b4 = *(const float4*)&auxB[ch0];
#pragma unroll
        for (int q = 0; q < 4; q++) {
          const size_t idx = ((size_t)bb * 512 + ch0 + q) * 4096 + p;
          OUTF[idx] = acc[mb][g * 4 + q] + auxA[idx] +
                      (q == 0 ? b4.x : q == 1 ? b4.y : q == 2 ? b4.z : b4.w);
        }
      }
  }
}

// ---------------- fused QK+V projections ----------------
__global__ __launch_bounds__(512, 2)
void k_qkv(const unsigned char* __restrict__ hn8, const unsigned char* __restrict__ Wqk8,
           const unsigned char* __restrict__ Wv8,
           unsigned char* __restrict__ qk8, unsigned char* __restrict__ vcm8,
           const float* __restrict__ bq, const float* __restrict__ bk,
           const float* __restrict__ bv){
  __shared__ __align__(16) unsigned char SMEM[32768];
  const int lin = blockIdx.x;
  const int nwg = gridDim.x;   // 1536
  const int wg = ((lin & 7) * (nwg >> 3)) + (lin >> 3);
  if (wg < 1024)
    gemm8_body<1>(wg, SMEM, Wqk8, hn8, qk8, nullptr, bq, bk, nullptr,
                  512, 512, 512, 0, 0, 8, 128);
  else
    gemm8_body<2>(wg - 1024, SMEM, hn8, Wv8, vcm8, nullptr, bv, nullptr, nullptr,
                  512, 512, 512, 0, 0, 128, 4);
}

// ---------------- PV (swapped, rinv inline) and O-proj (swapped, coalesced) ----------------
__global__ __launch_bounds__(512, 2)
void k_pv(const unsigned char* __restrict__ vcm8, const unsigned char* __restrict__ P8,
          unsigned char* __restrict__ ot8, const float* __restrict__ partial){
  __shared__ __align__(16) unsigned char SMEM[32768 + 2560];
  const int lin = blockIdx.x;
  const int nwg = gridDim.x;   // 512
  const int wg = ((lin & 7) * (nwg >> 3)) + (lin >> 3);
  gemm8_body<4>(wg, SMEM, vcm8, P8, ot8, nullptr, nullptr, nullptr, partial,
                4096, 4096, 4096,
                (size_t)512 * 4096, (size_t)4096 * 4096, 4, 32);
}
__global__ __launch_bounds__(512, 2)
void k_oproj(const unsigned char* __restrict__ Wo8, const unsigned char* __restrict__ ot8,
             float* __restrict__ out, const float* __restrict__ resid,
             const float* __restrict__ bo){
  __shared__ __align__(16) unsigned char SMEM[32768];
  const int lin = blockIdx.x;
  const int nwg = gridDim.x;   // 512
  const int wg = ((lin & 7) * (nwg >> 3)) + (lin >> 3);
  // A=Wo (512 ch, gx=4), B=ot8 (16384 tok, gy=128)
  gemm8_body<5>(wg, SMEM, Wo8, ot8, nullptr, out, resid, bo, nullptr,
                512, 512, 512, 0, 0, 4, 128);
}

// ---------------- scaled-fp8 scores, SWAPPED: S^T = K x Q^T ----------------
__global__ __launch_bounds__(512, 2)
void k_scores(const unsigned char* __restrict__ Kt, const unsigned char* __restrict__ Qt,
              unsigned char* __restrict__ C, const float* __restrict__ mask,
              float* __restrict__ partial, float scale,
              size_t sA, size_t sB, size_t sC, int gx, int gy)
{
  __shared__ __align__(16) unsigned char LDSBUF[65536];
  unsigned char* As = LDSBUF;
  unsigned char* Bs = LDSBUF + 32768;

  const int lin = blockIdx.x;
  const int nwg = gridDim.x;
  const int wg = ((lin & 7) * (nwg >> 3)) + (lin >> 3);
  const int bx = wg % gx;          // key block
  const int t2 = wg / gx;
  const int by = t2 % gy;          // query block
  const int bz = t2 / gy;

  const unsigned char* Ab = Kt + (size_t)bz * sA;
  const unsigned char* Bb = Qt + (size_t)bz * sB;
  const int brow = bx * 256;       // keys
  const int bcol = by * 256;       // queries
  const int t = threadIdx.x;
  const int lane = t & 63;
  const int wid = t >> 6;
  const int wr = wid >> 2;
  const int wc = wid & 3;
  const int l31 = lane & 31;
  const int lh  = lane >> 5;

  f32x16 acc[4][2];
#pragma unroll
  for (int m = 0; m < 4; m++)
#pragma unroll
    for (int n = 0; n < 2; n++)
#pragma unroll
      for (int e = 0; e < 16; e++) acc[m][n][e] = 0.f;

  const unsigned char* srcA[2];
  const unsigned char* srcB[2];
#pragma unroll
  for (int c = 0; c < 2; ++c) {
    const int q = c * 512 + t, r = q >> 2, s = (q & 3) ^ ((r >> 1) & 3);
    srcA[c] = Ab + (size_t)(brow + r) * 512 + s * 16;
    srcB[c] = Bb + (size_t)(bcol + r) * 512 + s * 16;
  }
  auto STAGE = [&](int kt, int buf) {
    const int ko = kt * 64;
#pragma unroll
    for (int c = 0; c < 2; ++c) {
      gl_lds16b(srcA[c] + ko, &As[buf * 16384 + (c * 512 + t) * 16]);
      gl_lds16b(srcB[c] + ko, &Bs[buf * 16384 + (c * 512 + t) * 16]);
    }
  };
  auto LDA32 = [&](int buf, int mb) -> i32x8 {
    const int ru = wr * 128 + mb * 32 + l31;
    const int x = (ru >> 1) & 3;
    const unsigned char* base = &As[buf * 16384 + ru * 64];
    i32x4 lo = *(const i32x4*)&base[((2 * lh) ^ x) * 16];
    i32x4 hi = *(const i32x4*)&base[((2 * lh + 1) ^ x) * 16];
    i32x8 r;
    r[0]=lo[0]; r[1]=lo[1]; r[2]=lo[2]; r[3]=lo[3];
    r[4]=hi[0]; r[5]=hi[1]; r[6]=hi[2]; r[7]=hi[3];
    return r;
  };
  auto LDB32 = [&](int buf, int nb) -> i32x8 {
    const int ru = wc * 64 + nb * 32 + l31;
    const int x = (ru >> 1) & 3;
    const unsigned char* base = &Bs[buf * 16384 + ru * 64];
    i32x4 lo = *(const i32x4*)&base[((2 * lh) ^ x) * 16];
    i32x4 hi = *(const i32x4*)&base[((2 * lh + 1) ^ x) * 16];
    i32x8 r;
    r[0]=lo[0]; r[1]=lo[1]; r[2]=lo[2]; r[3]=lo[3];
    r[4]=hi[0]; r[5]=hi[1]; r[6]=hi[2]; r[7]=hi[3];
    return r;
  };

  const int nk = 8;    // K=512
  STAGE(0, 0);
  for (int j = 0; j < nk; ++j) {
    const int bi = j & 1;
    asm volatile("s_waitcnt vmcnt(0)" ::: "memory");
    __builtin_amdgcn_s_barrier();
    __builtin_amdgcn_sched_barrier(0);
    if (j + 1 < nk) STAGE(j + 1, bi ^ 1);
    i32x8 aq[4], bq[2];
#pragma unroll
    for (int n = 0; n < 2; n++) bq[n] = LDB32(bi, n);
#pragma unroll
    for (int m = 0; m < 4; m++) aq[m] = LDA32(bi, m);
    asm volatile("s_waitcnt lgkmcnt(0)" ::: "memory");
    __builtin_amdgcn_sched_barrier(0);
    __builtin_amdgcn_s_setprio(1);
#pragma unroll
    for (int m = 0; m < 4; m++)
#pragma unroll
      for (int n = 0; n < 2; n++)
        acc[m][n] = mfma8_32x32x64(aq[m], bq[n], acc[m][n]);
    __builtin_amdgcn_s_setprio(0);
    __builtin_amdgcn_sched_barrier(0);
  }

  const float* maskb = mask + (size_t)bz * 4096;
  const float sc2 = scale * 1.4426950408889634f;

  asm volatile("s_waitcnt lgkmcnt(0)" ::: "memory");
  __builtin_amdgcn_s_barrier();

  float rs0 = 0.f, rs1 = 0.f;
#pragma unroll
  for (int mi = 0; mi < 4; mi++) {
#pragma unroll
    for (int g = 0; g < 4; g++) {
      const int kl0 = wr * 128 + mi * 32 + g * 8 + 4 * lh;
      const float4 m4 = *(const float4*)&maskb[brow + kl0];
      const int kp = perm64(kl0);
#pragma unroll
      for (int ni = 0; ni < 2; ni++) {
        const int reg = g * 4;
        float v0 = m4.x * fast_exp2(acc[mi][ni][reg + 0] * sc2);
        float v1 = m4.y * fast_exp2(acc[mi][ni][reg + 1] * sc2);
        float v2 = m4.z * fast_exp2(acc[mi][ni][reg + 2] * sc2);
        float v3 = m4.w * fast_exp2(acc[mi][ni][reg + 3] * sc2);
        if (ni == 0) rs0 += v0 + v1 + v2 + v3; else rs1 += v0 + v1 + v2 + v3;
        const int ql = wc * 64 + ni * 32 + l31;
        *(uint32_t*)&LDSBUF[ql * 256 + (kp ^ ((ql & 15) << 4))] = pack4(v0, v1, v2, v3);
      }
    }
  }
  rs0 += __shfl_xor(rs0, 32);
  rs1 += __shfl_xor(rs1, 32);
  if (lh == 0) {
    float* pslot = partial + ((size_t)bz * 32 + (size_t)(bx * 2 + wr)) * 4096;
    pslot[bcol + wc * 64 + l31]      = rs0;
    pslot[bcol + wc * 64 + 32 + l31] = rs1;
  }
  __builtin_amdgcn_s_barrier();
  unsigned char* Cb = C + (size_t)bz * sC;
#pragma unroll
  for (int i = 0; i < 8; i++) {
    const int ch = i * 512 + t;
    const int rl = ch >> 4;
    const int c16 = (ch & 15) * 16;
    i32x4 v = *(const i32x4*)&LDSBUF[rl * 256 + (c16 ^ ((rl & 15) << 4))];
    *(i32x4*)&Cb[(size_t)(bcol + rl) * 4096 + brow + c16] = v;
  }
}

extern "C" void kernel_launch(void* const* d_in, const int* in_sizes, int n_in,
                              void* d_out, int out_size, void* d_ws, size_t ws_size,
                              hipStream_t stream) {
  const float* x     = (const float*)d_in[0];
  const float* mask  = (const float*)d_in[1];
  const float* gamma = (const float*)d_in[2];
  const float* beta  = (const float*)d_in[3];
  const float* Wq    = (const float*)d_in[4];
  const float* bq    = (const float*)d_in[5];
  const float* Wk    = (const float*)d_in[6];
  const float* bk    = (const float*)d_in[7];
  const float* Wv    = (const float*)d_in[8];
  const float* bv    = (const float*)d_in[9];
  const float* Wo    = (const float*)d_in[10];
  const float* bo    = (const float*)d_in[11];
  float* out = (float*)d_out;

  size_t off = 0;
  auto nxt = [&](size_t bytes) -> void* {
    void* p = (char*)d_ws + off;
    off += (bytes + 255) & ~(size_t)255;
    return p;
  };
  float* spart          = (float*)nxt(2048 * sizeof(float));
  float* partial        = (float*)nxt((size_t)4 * 32 * 4096 * 4);
  unsigned char* Wqk8   = (unsigned char*)nxt((size_t)1024 * 512);
  unsigned char* Wv8    = (unsigned char*)nxt((size_t)512 * 512);
  unsigned char* Wo8    = (unsigned char*)nxt((size_t)512 * 512);
  unsigned char* hn8    = (unsigned char*)nxt((size_t)16384 * 512);
  unsigned char* qk8    = (unsigned char*)nxt((size_t)2 * 16384 * 512);
  unsigned char* vcm8   = (unsigned char*)nxt((size_t)4 * 512 * 4096);
  unsigned char* ot8    = (unsigned char*)nxt((size_t)16384 * 512);
  unsigned char* P8     = (unsigned char*)nxt((size_t)4 * 4096 * 4096);

  k_prep<<<1536, 256, 0, stream>>>(x, spart, Wq, Wk, Wv, Wo, Wqk8, Wv8, Wo8);
  gn_apply<<<dim3(128, 8, 4), 256, 0, stream>>>(x, spart, gamma, beta, hn8);
  k_qkv<<<1536, 512, 0, stream>>>(hn8, Wqk8, Wv8, qk8, vcm8, bq, bk, bv);
  k_scores<<<1024, 512, 0, stream>>>(qk8 + (size_t)8388608, qk8, P8, mask, partial,
                                     0.044194173824159216f,
                                     (size_t)4096 * 512, (size_t)4096 * 512,
                                     (size_t)4096 * 4096, 16, 16);
  k_pv<<<512, 512, 0, stream>>>(vcm8, P8, ot8, partial);
  k_oproj<<<512, 512, 0, stream>>>(Wo8, ot8, out, x, bo);
}